// Round 5
// baseline (105.171 us; speedup 1.0000x reference)
//
#include <hip/hip_runtime.h>

// LaneNet discriminative loss, MI355X — fused 2-kernel pipeline.
// preds: (4, 8, 280, 640) f32 ; targets: (4, 280, 640) i32 ; group_num = 5.
// out: [loss_dist, loss_var*0.01, loss_reg] f32.
//
// ws layout (floats):
//   [0, 700*45)          per-block k1 partials: block b -> 45 values
//                        (40 channel sums [g*8+c], 5 counts [40+g])
//   [31500, 31500+700)   per-block k2 var partials
//   [32200]              arrival counter (int), zeroed by k1
//
// Dispatch structure: k1 (accum partials) -> k2 (centers + var + last-block
// finalize). No memset, no global atomics on the hot path, no k_final.

#define P_TOTAL (280 * 640)   // 179200 = 175 * 256 * 4
#define NBATCH 4
#define GN 5
#define CC 8
#define NVAL (GN * CC + GN)   // 45
#define LPAD 47               // odd stride => conflict-free LDS transpose writes
#define NBX 175
#define NBLK (NBX * NBATCH)   // 700
#define WS_VP (NBLK * NVAL)   // 31500
#define WS_CNT (WS_VP + NBLK) // 32200 (int slot)

#define WAVE_RED(x)                          \
  do {                                       \
    x += __shfl_xor(x, 32, 64);              \
    x += __shfl_xor(x, 16, 64);              \
    x += __shfl_xor(x, 8, 64);               \
    x += __shfl_xor(x, 4, 64);               \
    x += __shfl_xor(x, 2, 64);               \
    x += __shfl_xor(x, 1, 64);               \
  } while (0)

__global__ __launch_bounds__(256) void k_accum(const float* __restrict__ preds,
                                               const int* __restrict__ targets,
                                               float* __restrict__ ws) {
  const int n = blockIdx.y;
  const int b = n * NBX + blockIdx.x;
  const int tid = threadIdx.x;
  const int p4 = (blockIdx.x * 256 + tid) * 4;   // exact: 175*256*4 = P_TOTAL

  // zero the k2 arrival counter (k1 fully completes before k2 starts)
  if (b == 0 && tid == 0) ((int*)ws)[WS_CNT] = 0;

  const float* pn = preds + (size_t)n * CC * P_TOTAL;
  const int* tn = targets + (size_t)n * P_TOTAL;

  float acc[GN][CC];
  float cnt[GN];
#pragma unroll
  for (int g = 0; g < GN; ++g) {
    cnt[g] = 0.0f;
#pragma unroll
    for (int c = 0; c < CC; ++c) acc[g][c] = 0.0f;
  }

  {
    int4 t4 = *reinterpret_cast<const int4*>(tn + p4);
    int t[4] = {t4.x, t4.y, t4.z, t4.w};
    float4 v4[CC];
#pragma unroll
    for (int c = 0; c < CC; ++c)
      v4[c] = *reinterpret_cast<const float4*>(pn + (size_t)c * P_TOTAL + p4);
    float v[CC][4];
#pragma unroll
    for (int c = 0; c < CC; ++c) {
      v[c][0] = v4[c].x; v[c][1] = v4[c].y; v[c][2] = v4[c].z; v[c][3] = v4[c].w;
    }
#pragma unroll
    for (int s = 0; s < 4; ++s) {
#pragma unroll
      for (int g = 0; g < GN; ++g) {
        float m = (t[s] == g + 1) ? 1.0f : 0.0f;
        cnt[g] += m;
#pragma unroll
        for (int c = 0; c < CC; ++c) acc[g][c] = fmaf(m, v[c][s], acc[g][c]);
      }
    }
  }

  // block reduction via LDS transpose
  __shared__ float buf[256][LPAD];
  __shared__ float part4[NVAL][4];
#pragma unroll
  for (int g = 0; g < GN; ++g) {
#pragma unroll
    for (int c = 0; c < CC; ++c) buf[tid][g * CC + c] = acc[g][c];
    buf[tid][GN * CC + g] = cnt[g];
  }
  __syncthreads();

  if (tid < NVAL * 4) {
    const int k = tid >> 2;
    const int part = tid & 3;
    float s = 0.0f;
#pragma unroll
    for (int r = 0; r < 64; ++r) s += buf[(r << 2) + part][k];
    part4[k][part] = s;
  }
  __syncthreads();

  if (tid < NVAL) {
    float s = part4[tid][0] + part4[tid][1] + part4[tid][2] + part4[tid][3];
    ws[b * NVAL + tid] = s;                     // private slot: no atomics
  }
}

__global__ __launch_bounds__(256) void k_var(const float* __restrict__ preds,
                                             const int* __restrict__ targets,
                                             float* __restrict__ ws,
                                             float* __restrict__ out) {
  const int n = blockIdx.y;
  const int b = n * NBX + blockIdx.x;
  const int tid = threadIdx.x;

  // ---- recompute this batch's centers from k1 partials (L2-hot) ----
  __shared__ float asum[NVAL];
  __shared__ float center[GN][CC];
  if (tid < NVAL) {
    float s = 0.0f;
    const float* base = ws + n * NBX * NVAL + tid;
    for (int r = 0; r < NBX; ++r) s += base[r * NVAL];
    asum[tid] = s;
  }
  __syncthreads();
  if (tid < GN * CC) {
    int g = tid >> 3;
    center[g][tid & 7] = asum[g * CC + (tid & 7)] / (asum[GN * CC + g] + 1e-5f);
  }
  __syncthreads();

  // ---- variance pass ----
  const float* pn = preds + (size_t)n * CC * P_TOTAL;
  const int* tn = targets + (size_t)n * P_TOTAL;
  const int p4 = (blockIdx.x * 256 + tid) * 4;

  float accv = 0.0f;
  {
    int4 t4 = *reinterpret_cast<const int4*>(tn + p4);
    int t[4] = {t4.x, t4.y, t4.z, t4.w};
    float4 v4[CC];
#pragma unroll
    for (int c = 0; c < CC; ++c)
      v4[c] = *reinterpret_cast<const float4*>(pn + (size_t)c * P_TOTAL + p4);
    float v[CC][4];
#pragma unroll
    for (int c = 0; c < CC; ++c) {
      v[c][0] = v4[c].x; v[c][1] = v4[c].y; v[c][2] = v4[c].z; v[c][3] = v4[c].w;
    }
#pragma unroll
    for (int s = 0; s < 4; ++s) {
      int ts = t[s];
      if (ts > 0) {
        int g = ts - 1;
        float ss = 0.0f;
#pragma unroll
        for (int c = 0; c < CC; ++c) {
          float d = v[c][s] - center[g][c];
          ss = fmaf(d, d, ss);
        }
        float dn = sqrtf(ss);
        float cl = fmaxf(dn - 0.2f, 0.0f);
        accv = fmaf(cl, cl, accv);
      }
    }
  }

  WAVE_RED(accv);
  __shared__ float red[4];
  __shared__ int isLast;
  const int lane = tid & 63;
  const int wv = tid >> 6;
  if (lane == 0) red[wv] = accv;
  __syncthreads();
  if (tid == 0) {
    float s = red[0] + red[1] + red[2] + red[3];
    ws[WS_VP + b] = s;                 // per-block var partial
    __threadfence();                   // release: partial visible device-wide
    int old = atomicAdd((int*)ws + WS_CNT, 1);
    isLast = (old == NBLK - 1) ? 1 : 0;
  }
  __syncthreads();
  if (!isLast) return;

  // ---- last-arriving block: finalize ----
  __threadfence();                     // acquire: see all blocks' partials

  __shared__ float fsum[NBATCH][NVAL];
  __shared__ float vsum[NBATCH];
  __shared__ float res[NBATCH][3];
  if (tid < NBATCH * NVAL) {
    const int n2 = tid / NVAL;
    const int k = tid % NVAL;
    float s = 0.0f;
    const float* base = ws + n2 * NBX * NVAL + k;
    for (int r = 0; r < NBX; ++r) s += base[r * NVAL];
    fsum[n2][k] = s;
  }
  {
    // per-n var sums: wave w handles batch w
    float s = 0.0f;
    for (int j = lane; j < NBX; j += 64) s += ws[WS_VP + wv * NBX + j];
    WAVE_RED(s);
    if (lane == 0) vsum[wv] = s;
  }
  __syncthreads();

  if (tid < NBATCH) {
    const int nn = tid;
    float cen[GN][CC];
    float has[GN];
    float ng = 0.0f;
#pragma unroll
    for (int g = 0; g < GN; ++g) {
      float c_ = fsum[nn][GN * CC + g];
      has[g] = (c_ > 0.0f) ? 1.0f : 0.0f;
      ng += has[g];
#pragma unroll
      for (int c = 0; c < CC; ++c)
        cen[g][c] = fsum[nn][g * CC + c] / (c_ + 1e-5f);
    }
    float lv = vsum[nn] / ng;
    float ld = 0.0f;
#pragma unroll
    for (int i = 0; i < GN; ++i) {
#pragma unroll
      for (int j = 0; j < GN; ++j) {
        float ss = 0.0f;
#pragma unroll
        for (int c = 0; c < CC; ++c) {
          float d = cen[j][c] - cen[i][c];
          ss = fmaf(d, d, ss);
        }
        float dn = (ss > 0.0f) ? sqrtf(ss) : 0.0f;
        float cl = fmaxf(1.2f - dn, 0.0f);
        ld += cl * cl * has[i];
      }
    }
    ld /= fmaxf(ng * (ng - 1.0f), 1.0f);
    float lr = 0.0f;
#pragma unroll
    for (int g = 0; g < GN; ++g) {
      float cs = 0.0f;
#pragma unroll
      for (int c = 0; c < CC; ++c) cs += cen[g][c];
      lr += cs * cs * has[g];
    }
    res[nn][0] = ld;
    res[nn][1] = lv;
    res[nn][2] = lr;
  }
  __syncthreads();
  if (tid == 0) {
    float d = 0.0f, v = 0.0f, r = 0.0f;
#pragma unroll
    for (int nn = 0; nn < NBATCH; ++nn) {
      d += res[nn][0]; v += res[nn][1]; r += res[nn][2];
    }
    out[0] = d * 0.25f;
    out[1] = v * 0.25f * 0.01f;
    out[2] = r * 0.001f;
  }
}

extern "C" void kernel_launch(void* const* d_in, const int* in_sizes, int n_in,
                              void* d_out, int out_size, void* d_ws, size_t ws_size,
                              hipStream_t stream) {
  const float* preds = (const float*)d_in[0];
  const int* targets = (const int*)d_in[1];
  float* out = (float*)d_out;
  float* ws = (float*)d_ws;

  dim3 grid(NBX, NBATCH);   // (175, 4)
  k_accum<<<grid, 256, 0, stream>>>(preds, targets, ws);
  k_var<<<grid, 256, 0, stream>>>(preds, targets, ws, out);
}

// Round 6
// 93.508 us; speedup vs baseline: 1.1247x; 1.1247x over previous
//
#include <hip/hip_runtime.h>

// LaneNet discriminative loss, MI355X — 4-kernel atomic-free pipeline.
// preds: (4, 8, 280, 640) f32 ; targets: (4, 280, 640) i32 ; group_num = 5.
// out: [loss_dist, loss_var*0.01, loss_reg] f32.
//
// ws layout (floats):
//   PART [0, 700*45)        per-block k1 partials (40 sums, 5 counts)
//   VP   [31500, 32200)     per-block k2 var partials
//   CEN  [32200, 32200+4*48) per-batch: 40 centers (divided) + 5 counts + 3 pad
//
// No atomics, no memset: every cross-block handoff is a plain store
// + kernel boundary (inter-dispatch acquire/release handles coherence).

#define P_TOTAL (280 * 640)   // 179200 = 175 * 256 * 4
#define NBATCH 4
#define GN 5
#define CC 8
#define NVAL (GN * CC + GN)   // 45
#define LPAD 47               // odd stride => conflict-free LDS transpose
#define NBX 175
#define NBLK (NBX * NBATCH)   // 700
#define WS_VP (NBLK * NVAL)   // 31500
#define WS_CEN (WS_VP + NBLK) // 32200
#define CEN_STRIDE 48

#define WAVE_RED(x)                          \
  do {                                       \
    x += __shfl_xor(x, 32, 64);              \
    x += __shfl_xor(x, 16, 64);              \
    x += __shfl_xor(x, 8, 64);               \
    x += __shfl_xor(x, 4, 64);               \
    x += __shfl_xor(x, 2, 64);               \
    x += __shfl_xor(x, 1, 64);               \
  } while (0)

__global__ __launch_bounds__(256) void k_accum(const float* __restrict__ preds,
                                               const int* __restrict__ targets,
                                               float* __restrict__ ws) {
  const int n = blockIdx.y;
  const int b = n * NBX + blockIdx.x;
  const int tid = threadIdx.x;
  const int p4 = (blockIdx.x * 256 + tid) * 4;   // exact: 175*256*4 = P_TOTAL

  const float* pn = preds + (size_t)n * CC * P_TOTAL;
  const int* tn = targets + (size_t)n * P_TOTAL;

  float acc[GN][CC];
  float cnt[GN];
#pragma unroll
  for (int g = 0; g < GN; ++g) {
    cnt[g] = 0.0f;
#pragma unroll
    for (int c = 0; c < CC; ++c) acc[g][c] = 0.0f;
  }

  {
    int4 t4 = *reinterpret_cast<const int4*>(tn + p4);
    int t[4] = {t4.x, t4.y, t4.z, t4.w};
    float4 v4[CC];
#pragma unroll
    for (int c = 0; c < CC; ++c)
      v4[c] = *reinterpret_cast<const float4*>(pn + (size_t)c * P_TOTAL + p4);
    float v[CC][4];
#pragma unroll
    for (int c = 0; c < CC; ++c) {
      v[c][0] = v4[c].x; v[c][1] = v4[c].y; v[c][2] = v4[c].z; v[c][3] = v4[c].w;
    }
#pragma unroll
    for (int s = 0; s < 4; ++s) {
#pragma unroll
      for (int g = 0; g < GN; ++g) {
        float m = (t[s] == g + 1) ? 1.0f : 0.0f;
        cnt[g] += m;
#pragma unroll
        for (int c = 0; c < CC; ++c) acc[g][c] = fmaf(m, v[c][s], acc[g][c]);
      }
    }
  }

  // block reduction via LDS transpose
  __shared__ float buf[256][LPAD];
  __shared__ float part4[NVAL][4];
#pragma unroll
  for (int g = 0; g < GN; ++g) {
#pragma unroll
    for (int c = 0; c < CC; ++c) buf[tid][g * CC + c] = acc[g][c];
    buf[tid][GN * CC + g] = cnt[g];
  }
  __syncthreads();

  if (tid < NVAL * 4) {
    const int k = tid >> 2;
    const int part = tid & 3;
    float s = 0.0f;
#pragma unroll
    for (int r = 0; r < 64; ++r) s += buf[(r << 2) + part][k];
    part4[k][part] = s;
  }
  __syncthreads();

  if (tid < NVAL) {
    ws[b * NVAL + tid] =
        part4[tid][0] + part4[tid][1] + part4[tid][2] + part4[tid][3];
  }
}

// 4 blocks (one per batch): reduce 175 partial-sets -> centers + counts.
__global__ __launch_bounds__(256) void k_center(float* __restrict__ ws) {
  const int n = blockIdx.x;
  const int tid = threadIdx.x;
  __shared__ float p4s[NVAL][4];
  __shared__ float tots[NVAL];
  if (tid < NVAL * 4) {
    const int k = tid >> 2;
    const int part = tid & 3;
    float s = 0.0f;
    const float* base = ws + (n * NBX) * NVAL + k;
    for (int r = part; r < NBX; r += 4) s += base[r * NVAL];
    p4s[k][part] = s;
  }
  __syncthreads();
  if (tid < NVAL)
    tots[tid] = p4s[tid][0] + p4s[tid][1] + p4s[tid][2] + p4s[tid][3];
  __syncthreads();
  if (tid < GN * CC)
    ws[WS_CEN + n * CEN_STRIDE + tid] =
        tots[tid] / (tots[GN * CC + (tid >> 3)] + 1e-5f);
  else if (tid < NVAL)
    ws[WS_CEN + n * CEN_STRIDE + tid] = tots[tid];   // counts
}

__global__ __launch_bounds__(256) void k_var(const float* __restrict__ preds,
                                             const int* __restrict__ targets,
                                             float* __restrict__ ws) {
  const int n = blockIdx.y;
  const int b = n * NBX + blockIdx.x;
  const int tid = threadIdx.x;

  __shared__ float center[GN][CC];
  if (tid < GN * CC)
    center[tid >> 3][tid & 7] = ws[WS_CEN + n * CEN_STRIDE + tid];
  __syncthreads();

  const float* pn = preds + (size_t)n * CC * P_TOTAL;
  const int* tn = targets + (size_t)n * P_TOTAL;
  const int p4 = (blockIdx.x * 256 + tid) * 4;

  float accv = 0.0f;
  {
    int4 t4 = *reinterpret_cast<const int4*>(tn + p4);
    int t[4] = {t4.x, t4.y, t4.z, t4.w};
    float4 v4[CC];
#pragma unroll
    for (int c = 0; c < CC; ++c)
      v4[c] = *reinterpret_cast<const float4*>(pn + (size_t)c * P_TOTAL + p4);
    float v[CC][4];
#pragma unroll
    for (int c = 0; c < CC; ++c) {
      v[c][0] = v4[c].x; v[c][1] = v4[c].y; v[c][2] = v4[c].z; v[c][3] = v4[c].w;
    }
#pragma unroll
    for (int s = 0; s < 4; ++s) {
      int ts = t[s];
      if (ts > 0) {
        int g = ts - 1;
        float ss = 0.0f;
#pragma unroll
        for (int c = 0; c < CC; ++c) {
          float d = v[c][s] - center[g][c];
          ss = fmaf(d, d, ss);
        }
        float dn = sqrtf(ss);
        float cl = fmaxf(dn - 0.2f, 0.0f);
        accv = fmaf(cl, cl, accv);
      }
    }
  }

  WAVE_RED(accv);
  __shared__ float red[4];
  const int lane = tid & 63;
  const int wv = tid >> 6;
  if (lane == 0) red[wv] = accv;
  __syncthreads();
  if (tid == 0)
    ws[WS_VP + b] = red[0] + red[1] + red[2] + red[3];
}

__global__ __launch_bounds__(256) void k_final(const float* __restrict__ ws,
                                               float* __restrict__ out) {
  const int tid = threadIdx.x;
  const int lane = tid & 63;
  const int wv = tid >> 6;

  __shared__ float vsum[NBATCH];
  __shared__ float res[NBATCH][3];
  {
    // wave w sums batch w's 175 var partials
    float s = 0.0f;
    for (int j = lane; j < NBX; j += 64) s += ws[WS_VP + wv * NBX + j];
    WAVE_RED(s);
    if (lane == 0) vsum[wv] = s;
  }
  __syncthreads();

  if (tid < NBATCH) {
    const int n = tid;
    const float* cb = ws + WS_CEN + n * CEN_STRIDE;
    float cen[GN][CC];
    float has[GN];
    float ng = 0.0f;
#pragma unroll
    for (int g = 0; g < GN; ++g) {
      has[g] = (cb[GN * CC + g] > 0.0f) ? 1.0f : 0.0f;
      ng += has[g];
#pragma unroll
      for (int c = 0; c < CC; ++c) cen[g][c] = cb[g * CC + c];
    }
    float lv = vsum[n] / ng;
    float ld = 0.0f;
#pragma unroll
    for (int i = 0; i < GN; ++i) {
#pragma unroll
      for (int j = 0; j < GN; ++j) {
        float ss = 0.0f;
#pragma unroll
        for (int c = 0; c < CC; ++c) {
          float d = cen[j][c] - cen[i][c];
          ss = fmaf(d, d, ss);
        }
        float dn = (ss > 0.0f) ? sqrtf(ss) : 0.0f;
        float cl = fmaxf(1.2f - dn, 0.0f);
        ld += cl * cl * has[i];
      }
    }
    ld /= fmaxf(ng * (ng - 1.0f), 1.0f);
    float lr = 0.0f;
#pragma unroll
    for (int g = 0; g < GN; ++g) {
      float cs = 0.0f;
#pragma unroll
      for (int c = 0; c < CC; ++c) cs += cen[g][c];
      lr += cs * cs * has[g];
    }
    res[n][0] = ld;
    res[n][1] = lv;
    res[n][2] = lr;
  }
  __syncthreads();
  if (tid == 0) {
    float d = 0.0f, v = 0.0f, r = 0.0f;
#pragma unroll
    for (int n = 0; n < NBATCH; ++n) {
      d += res[n][0]; v += res[n][1]; r += res[n][2];
    }
    out[0] = d * 0.25f;
    out[1] = v * 0.25f * 0.01f;
    out[2] = r * 0.001f;
  }
}

extern "C" void kernel_launch(void* const* d_in, const int* in_sizes, int n_in,
                              void* d_out, int out_size, void* d_ws, size_t ws_size,
                              hipStream_t stream) {
  const float* preds = (const float*)d_in[0];
  const int* targets = (const int*)d_in[1];
  float* out = (float*)d_out;
  float* ws = (float*)d_ws;

  dim3 grid(NBX, NBATCH);   // (175, 4)
  k_accum<<<grid, 256, 0, stream>>>(preds, targets, ws);
  k_center<<<NBATCH, 256, 0, stream>>>(ws);
  k_var<<<grid, 256, 0, stream>>>(preds, targets, ws);
  k_final<<<1, 256, 0, stream>>>(ws, out);
}

// Round 9
// 82.780 us; speedup vs baseline: 1.2705x; 1.1296x over previous
//
#include <hip/hip_runtime.h>

// LaneNet discriminative loss, MI355X — 3-dispatch pipeline, ILP-safe reductions.
// preds: (4, 8, 280, 640) f32 ; targets: (4, 280, 640) i32 ; group_num = 5.
// out: [loss_dist, loss_var*0.01, loss_reg] f32.
//
// ws floats: PART [0, 700*45) ; VP [31500, 32200) ; CEN [32200, +4*48)
// All cross-block handoffs are plain stores + kernel boundary (coherent).
// NOTE: no serial dependent-load loops — every partial-reduce splits rows
// across parts so each thread's loads are independent (vmcnt-pipelined).

#define P_TOTAL (280 * 640)   // 179200 = 175 * 256 * 4
#define NBATCH 4
#define GN 5
#define CC 8
#define NVAL (GN * CC + GN)   // 45
#define LPAD 47               // odd stride => conflict-free LDS transpose
#define NBX 175
#define NUNIT (NBX * NBATCH)  // 700
#define WS_VP (NUNIT * NVAL)  // 31500
#define WS_CEN (WS_VP + NUNIT)
#define CEN_STRIDE 48

#define WAVE_RED(x)                          \
  do {                                       \
    x += __shfl_xor(x, 32, 64);              \
    x += __shfl_xor(x, 16, 64);              \
    x += __shfl_xor(x, 8, 64);               \
    x += __shfl_xor(x, 4, 64);               \
    x += __shfl_xor(x, 2, 64);               \
    x += __shfl_xor(x, 1, 64);               \
  } while (0)

__global__ __launch_bounds__(256) void k_accum(const float* __restrict__ preds,
                                               const int* __restrict__ targets,
                                               float* __restrict__ ws) {
  const int n = blockIdx.y;
  const int u = n * NBX + blockIdx.x;
  const int tid = threadIdx.x;
  const int p4 = (blockIdx.x * 256 + tid) * 4;   // exact: 175*256*4 = P_TOTAL

  const float* pn = preds + (size_t)n * CC * P_TOTAL;
  const int* tn = targets + (size_t)n * P_TOTAL;

  float acc[GN][CC];
  float cnt[GN];
#pragma unroll
  for (int g = 0; g < GN; ++g) {
    cnt[g] = 0.0f;
#pragma unroll
    for (int c = 0; c < CC; ++c) acc[g][c] = 0.0f;
  }

  {
    int4 t4 = *reinterpret_cast<const int4*>(tn + p4);
    int t[4] = {t4.x, t4.y, t4.z, t4.w};
    float4 v4[CC];
#pragma unroll
    for (int c = 0; c < CC; ++c)
      v4[c] = *reinterpret_cast<const float4*>(pn + (size_t)c * P_TOTAL + p4);
    float v[CC][4];
#pragma unroll
    for (int c = 0; c < CC; ++c) {
      v[c][0] = v4[c].x; v[c][1] = v4[c].y; v[c][2] = v4[c].z; v[c][3] = v4[c].w;
    }
#pragma unroll
    for (int s = 0; s < 4; ++s) {
#pragma unroll
      for (int g = 0; g < GN; ++g) {
        float m = (t[s] == g + 1) ? 1.0f : 0.0f;
        cnt[g] += m;
#pragma unroll
        for (int c = 0; c < CC; ++c) acc[g][c] = fmaf(m, v[c][s], acc[g][c]);
      }
    }
  }

  // block reduction via LDS transpose
  __shared__ float buf[256][LPAD];
  __shared__ float part4[NVAL][4];
#pragma unroll
  for (int g = 0; g < GN; ++g) {
#pragma unroll
    for (int c = 0; c < CC; ++c) buf[tid][g * CC + c] = acc[g][c];
    buf[tid][GN * CC + g] = cnt[g];
  }
  __syncthreads();

  if (tid < NVAL * 4) {
    const int k = tid >> 2;
    const int part = tid & 3;
    float s = 0.0f;
#pragma unroll
    for (int r = 0; r < 64; ++r) s += buf[(r << 2) + part][k];
    part4[k][part] = s;
  }
  __syncthreads();

  if (tid < NVAL)
    ws[u * NVAL + tid] =
        part4[tid][0] + part4[tid][1] + part4[tid][2] + part4[tid][3];
}

__global__ __launch_bounds__(256) void k_var(const float* __restrict__ preds,
                                             const int* __restrict__ targets,
                                             float* __restrict__ ws) {
  const int n = blockIdx.y;
  const int u = n * NBX + blockIdx.x;
  const int tid = threadIdx.x;

  // ---- per-block center recompute from partials (L2-hot, ILP-deep) ----
  // 225 threads: (k, part) ; part covers 35 rows each ; loads independent.
  __shared__ float sums[NVAL][6];   // [k][part], padded
  __shared__ float tots[NVAL];
  __shared__ float center[GN][CC];
  if (tid < NVAL * 5) {
    const int k = tid % NVAL;
    const int part = tid / NVAL;    // 0..4
    const float* base = ws + ((size_t)n * NBX + part * 35) * NVAL + k;
    float s = 0.0f;
#pragma unroll
    for (int i = 0; i < 35; ++i) s += base[i * NVAL];
    sums[k][part] = s;
  }
  __syncthreads();
  if (tid < NVAL)
    tots[tid] = sums[tid][0] + sums[tid][1] + sums[tid][2] + sums[tid][3] +
                sums[tid][4];
  __syncthreads();
  if (tid < GN * CC)
    center[tid >> 3][tid & 7] = tots[tid] / (tots[GN * CC + (tid >> 3)] + 1e-5f);
  __syncthreads();

  // block bx==0 persists centers+counts for k_final
  if (blockIdx.x == 0 && tid < NVAL) {
    ws[WS_CEN + n * CEN_STRIDE + tid] =
        (tid < GN * CC) ? center[tid >> 3][tid & 7] : tots[tid];
  }

  // ---- variance pass ----
  const float* pn = preds + (size_t)n * CC * P_TOTAL;
  const int* tn = targets + (size_t)n * P_TOTAL;
  const int p4 = (blockIdx.x * 256 + tid) * 4;

  float accv = 0.0f;
  {
    int4 t4 = *reinterpret_cast<const int4*>(tn + p4);
    int t[4] = {t4.x, t4.y, t4.z, t4.w};
    float4 v4[CC];
#pragma unroll
    for (int c = 0; c < CC; ++c)
      v4[c] = *reinterpret_cast<const float4*>(pn + (size_t)c * P_TOTAL + p4);
    float v[CC][4];
#pragma unroll
    for (int c = 0; c < CC; ++c) {
      v[c][0] = v4[c].x; v[c][1] = v4[c].y; v[c][2] = v4[c].z; v[c][3] = v4[c].w;
    }
#pragma unroll
    for (int s = 0; s < 4; ++s) {
      int ts = t[s];
      if (ts > 0) {
        int g = ts - 1;
        float ss = 0.0f;
#pragma unroll
        for (int c = 0; c < CC; ++c) {
          float d = v[c][s] - center[g][c];
          ss = fmaf(d, d, ss);
        }
        float dn = sqrtf(ss);
        float cl = fmaxf(dn - 0.2f, 0.0f);
        accv = fmaf(cl, cl, accv);
      }
    }
  }

  WAVE_RED(accv);
  __shared__ float red[4];
  const int lane = tid & 63;
  const int wv = tid >> 6;
  if (lane == 0) red[wv] = accv;
  __syncthreads();
  if (tid == 0)
    ws[WS_VP + u] = red[0] + red[1] + red[2] + red[3];
}

__global__ __launch_bounds__(256) void k_final(const float* __restrict__ ws,
                                               float* __restrict__ out) {
  const int tid = threadIdx.x;
  const int lane = tid & 63;
  const int wv = tid >> 6;

  __shared__ float vsum[NBATCH];
  __shared__ float res[NBATCH][3];
  {
    // wave w sums batch w's 175 var partials (3 independent loads/lane)
    float s = 0.0f;
    for (int j = lane; j < NBX; j += 64) s += ws[WS_VP + wv * NBX + j];
    WAVE_RED(s);
    if (lane == 0) vsum[wv] = s;
  }
  __syncthreads();

  if (tid < NBATCH) {
    const int n = tid;
    const float* cb = ws + WS_CEN + n * CEN_STRIDE;
    float cen[GN][CC];
    float has[GN];
    float ng = 0.0f;
#pragma unroll
    for (int g = 0; g < GN; ++g) {
      has[g] = (cb[GN * CC + g] > 0.0f) ? 1.0f : 0.0f;
      ng += has[g];
#pragma unroll
      for (int c = 0; c < CC; ++c) cen[g][c] = cb[g * CC + c];
    }
    float lv = vsum[n] / ng;
    float ld = 0.0f;
#pragma unroll
    for (int i = 0; i < GN; ++i) {
#pragma unroll
      for (int j = 0; j < GN; ++j) {
        float ss = 0.0f;
#pragma unroll
        for (int c = 0; c < CC; ++c) {
          float d = cen[j][c] - cen[i][c];
          ss = fmaf(d, d, ss);
        }
        float dn = (ss > 0.0f) ? sqrtf(ss) : 0.0f;
        float cl = fmaxf(1.2f - dn, 0.0f);
        ld += cl * cl * has[i];
      }
    }
    ld /= fmaxf(ng * (ng - 1.0f), 1.0f);
    float lr = 0.0f;
#pragma unroll
    for (int g = 0; g < GN; ++g) {
      float cs = 0.0f;
#pragma unroll
      for (int c = 0; c < CC; ++c) cs += cen[g][c];
      lr += cs * cs * has[g];
    }
    res[n][0] = ld;
    res[n][1] = lv;
    res[n][2] = lr;
  }
  __syncthreads();
  if (tid == 0) {
    float d = 0.0f, v = 0.0f, r = 0.0f;
#pragma unroll
    for (int n = 0; n < NBATCH; ++n) {
      d += res[n][0]; v += res[n][1]; r += res[n][2];
    }
    out[0] = d * 0.25f;
    out[1] = v * 0.25f * 0.01f;
    out[2] = r * 0.001f;
  }
}

extern "C" void kernel_launch(void* const* d_in, const int* in_sizes, int n_in,
                              void* d_out, int out_size, void* d_ws, size_t ws_size,
                              hipStream_t stream) {
  const float* preds = (const float*)d_in[0];
  const int* targets = (const int*)d_in[1];
  float* out = (float*)d_out;
  float* ws = (float*)d_ws;

  dim3 grid(NBX, NBATCH);   // (175, 4)
  k_accum<<<grid, 256, 0, stream>>>(preds, targets, ws);
  k_var<<<grid, 256, 0, stream>>>(preds, targets, ws);
  k_final<<<1, 256, 0, stream>>>(ws, out);
}